// Round 1
// baseline (1337.895 us; speedup 1.0000x reference)
//
#include <hip/hip_runtime.h>

typedef __attribute__((ext_vector_type(8))) short short8;
typedef __attribute__((ext_vector_type(4))) float fx4;

__device__ __forceinline__ unsigned short f32_to_bf16_rne(float f){
  unsigned int u = __float_as_uint(f);
  u += 0x7fffu + ((u >> 16) & 1u);
  return (unsigned short)(u >> 16);
}

// ---------------- convert f32 -> bf16 (flat) ----------------
__global__ void cvt_bf16(const float* __restrict__ in, unsigned short* __restrict__ out, int n4){
  int i = blockIdx.x * blockDim.x + threadIdx.x;
  if (i < n4){
    float4 v = ((const float4*)in)[i];
    ushort4 o;
    o.x = f32_to_bf16_rne(v.x); o.y = f32_to_bf16_rne(v.y);
    o.z = f32_to_bf16_rne(v.z); o.w = f32_to_bf16_rne(v.w);
    ((ushort4*)out)[i] = o;
  }
}

// ---------------- transpose + convert: in[R][C] f32 -> out[C][R] bf16 ----------------
__global__ void transpose_cvt(const float* __restrict__ in, unsigned short* __restrict__ out,
                              int R, int C){
  __shared__ float tile[32][33];
  int c0 = blockIdx.x * 32, r0 = blockIdx.y * 32;
  int lc = threadIdx.x & 31, lr = threadIdx.x >> 5;   // 8 row-groups
  #pragma unroll
  for (int i = 0; i < 32; i += 8)
    tile[lr + i][lc] = in[(size_t)(r0 + lr + i) * C + c0 + lc];
  __syncthreads();
  #pragma unroll
  for (int i = 0; i < 32; i += 8)
    out[(size_t)(c0 + lr + i) * R + r0 + lc] = f32_to_bf16_rne(tile[lc][lr + i]);
}

// ---------------- bf16 MFMA GEMM: C[M][N] = A[M][K] * BT[N][K]^T + bias ----------------
// MODE 0: out[row*N+col] = val   (proj -> d_out)
// MODE 1: qkv scatter: col -> (which,h,d), row -> (b,t); out = qkv base [3][B][H][T][D]
template<int MODE>
__global__ __launch_bounds__(256) void gemm_bf16(const unsigned short* __restrict__ A,
    const unsigned short* __restrict__ BT, const float* __restrict__ bias,
    float* __restrict__ out, int M, int N, int K)
{
  __shared__ unsigned short a_s[2][128 * 32];
  __shared__ unsigned short b_s[2][128 * 32];
  const int tid = threadIdx.x;
  const int brow = blockIdx.x * 128, bcol = blockIdx.y * 128;
  const int lane = tid & 63;
  const int wave = tid >> 6;
  const int wm = (wave >> 1) * 64, wn = (wave & 1) * 64;
  const int lanr = lane & 15, laneq = lane >> 4;

  fx4 acc[4][4];
  const fx4 zero = {0.f, 0.f, 0.f, 0.f};
  #pragma unroll
  for (int m = 0; m < 4; m++)
    #pragma unroll
    for (int n = 0; n < 4; n++) acc[m][n] = zero;

  short8 ra[2], rb[2];
  auto gload = [&](int k0){
    #pragma unroll
    for (int i = 0; i < 2; i++){
      int cc = tid + (i << 8);
      int row = cc >> 2, seg = (cc & 3) << 3;
      ra[i] = *(const short8*)(A  + (size_t)(brow + row) * K + k0 + seg);
      rb[i] = *(const short8*)(BT + (size_t)(bcol + row) * K + k0 + seg);
    }
  };
  auto lwrite = [&](int bufi){
    #pragma unroll
    for (int i = 0; i < 2; i++){
      int cc = tid + (i << 8);
      *(short8*)&a_s[bufi][cc * 8] = ra[i];
      *(short8*)&b_s[bufi][cc * 8] = rb[i];
    }
  };

  gload(0); lwrite(0); __syncthreads();
  const int NT = K / 32;
  int buf = 0;
  for (int t = 0; t < NT; t++){
    if (t + 1 < NT) gload((t + 1) * 32);
    short8 af[4], bfr[4];
    #pragma unroll
    for (int m = 0; m < 4; m++)
      af[m] = *(short8*)&a_s[buf][(wm + m * 16 + lanr) * 32 + laneq * 8];
    #pragma unroll
    for (int n = 0; n < 4; n++)
      bfr[n] = *(short8*)&b_s[buf][(wn + n * 16 + lanr) * 32 + laneq * 8];
    #pragma unroll
    for (int m = 0; m < 4; m++)
      #pragma unroll
      for (int n = 0; n < 4; n++)
        acc[m][n] = __builtin_amdgcn_mfma_f32_16x16x32_bf16(af[m], bfr[n], acc[m][n], 0, 0, 0);
    __syncthreads();
    if (t + 1 < NT){ lwrite(buf ^ 1); __syncthreads(); }
    buf ^= 1;
  }

  #pragma unroll
  for (int m = 0; m < 4; m++){
    #pragma unroll
    for (int n = 0; n < 4; n++){
      const int col = bcol + wn + n * 16 + lanr;
      const float bv = bias[col];
      #pragma unroll
      for (int r = 0; r < 4; r++){
        const int row = brow + wm + m * 16 + laneq * 4 + r;
        const float val = acc[m][n][r] + bv;
        if constexpr (MODE == 0){
          out[(size_t)row * N + col] = val;
        } else {
          const int which = col >> 10, cc2 = col & 1023;
          const int hh = cc2 >> 6, dd = cc2 & 63;
          const int bb = row >> 10, tt2 = row & 1023;
          out[((((size_t)which * 4 + bb) * 16 + hh) * 1024 + tt2) * 64 + dd] = val;
        }
      }
    }
  }
}

// ---------------- lr2[b,h,n,s] = 0.125 * dot(LR_Q[h,n], k[b,h,s]) ----------------
__global__ __launch_bounds__(64) void lr2_kernel(const float* __restrict__ LRQ,
    const float* __restrict__ kg, float* __restrict__ lr2g)
{
  __shared__ float ks[64][68];
  __shared__ float lq[16][68];
  const int lane = threadIdx.x;
  const int s0 = blockIdx.x << 6;
  const int ngrp = blockIdx.y;     // 0..3
  const int bh = blockIdx.z;       // 0..63
  const int h = bh & 15;
  for (int r = 0; r < 64; r++)
    ks[r][lane] = kg[((size_t)(bh * 1024 + s0 + r)) * 64 + lane];
  for (int r = 0; r < 16; r++)
    lq[r][lane] = LRQ[((size_t)(h * 64 + (ngrp << 4) + r)) * 64 + lane];
  __syncthreads();
  float4 kr[16];
  #pragma unroll
  for (int j = 0; j < 16; j++) kr[j] = *(float4*)&ks[lane][j << 2];
  #pragma unroll
  for (int n = 0; n < 16; n++){
    float a = 0.f;
    #pragma unroll
    for (int j = 0; j < 16; j++){
      float4 l4 = *(float4*)&lq[n][j << 2];
      a += l4.x * kr[j].x + l4.y * kr[j].y + l4.z * kr[j].z + l4.w * kr[j].w;
    }
    lr2g[((size_t)(bh * 64 + (ngrp << 4) + n)) * 1024 + s0 + lane] = a * 0.125f;
  }
}

// ---------------- fused relative attention ----------------
// block = (b, h, 16-row t-tile); bid = ((b*64 + tt)*16 + h)  (h innermost for L2 reuse of rel/LR_map)
__global__ __launch_bounds__(256, 1) void attn_kernel(
    const float* __restrict__ qg, const float* __restrict__ kg, const float* __restrict__ vg,
    const int* __restrict__ rel, const float* __restrict__ tds,
    const float* __restrict__ relw, const int* __restrict__ lrmap,
    const float* __restrict__ LRK, const float* __restrict__ lr2g,
    const float* __restrict__ rke, const float* __restrict__ rve,
    unsigned short* __restrict__ yb)
{
  __shared__ float p_s[16][1028];
  __shared__ float kv_s[128][68];
  __shared__ float lr2_s[64][132];
  __shared__ float q_s[16][68];
  __shared__ float lr1_s[16][64];
  __shared__ float qrk_s[16][36];
  __shared__ float rv_s[33][68];
  __shared__ float relw_s[64];
  __shared__ float S_s[16];

  const int tid = threadIdx.x;
  const int bid = blockIdx.x;
  const int h = bid & 15;
  const int tmp = bid >> 4;
  const int tt = tmp & 63;
  const int b = tmp >> 6;
  const int t0 = tt << 4;
  const int bh = (b << 4) + h;
  const int lane = tid & 63;
  const int wave = tid >> 6;

  // stage tables
  if (tid < 64) relw_s[tid] = relw[tid * 16 + h];
  {
    int i = tid >> 4, d0 = (tid & 15) << 2;
    *(float4*)&q_s[i][d0] = *(const float4*)&qg[((size_t)(bh * 1024 + t0 + i)) * 64 + d0];
  }
  for (int c = tid; c < 33 * 16; c += 256){
    int r = c >> 4, d0 = (c & 15) << 2;
    *(float4*)&rv_s[r][d0] = *(const float4*)&rve[r * 64 + d0];
  }
  for (int c = tid; c < 64 * 16; c += 256){  // LR_K[h] staged temporarily in kv_s
    int r = c >> 4, d0 = (c & 15) << 2;
    *(float4*)&kv_s[r][d0] = *(const float4*)&LRK[((size_t)(h * 64 + r)) * 64 + d0];
  }
  __syncthreads();

  // lr1[i][n] = 0.125 * dot(q[i], LR_K[h][n])
  {
    int i = tid >> 4, n0 = (tid & 15) << 2;
    float a0 = 0, a1 = 0, a2 = 0, a3 = 0;
    #pragma unroll
    for (int d = 0; d < 64; d += 4){
      float4 qv = *(float4*)&q_s[i][d];
      float4 x0 = *(float4*)&kv_s[n0 + 0][d];
      float4 x1 = *(float4*)&kv_s[n0 + 1][d];
      float4 x2 = *(float4*)&kv_s[n0 + 2][d];
      float4 x3 = *(float4*)&kv_s[n0 + 3][d];
      a0 += qv.x * x0.x + qv.y * x0.y + qv.z * x0.z + qv.w * x0.w;
      a1 += qv.x * x1.x + qv.y * x1.y + qv.z * x1.z + qv.w * x1.w;
      a2 += qv.x * x2.x + qv.y * x2.y + qv.z * x2.z + qv.w * x2.w;
      a3 += qv.x * x3.x + qv.y * x3.y + qv.z * x3.z + qv.w * x3.w;
    }
    lr1_s[i][n0 + 0] = a0 * 0.125f;
    lr1_s[i][n0 + 1] = a1 * 0.125f;
    lr1_s[i][n0 + 2] = a2 * 0.125f;
    lr1_s[i][n0 + 3] = a3 * 0.125f;
  }
  // qrk[i][r] = dot(q[i], rel_k_emb[r]), r in [0,33)
  {
    int i = tid >> 4;
    for (int r = tid & 15; r < 33; r += 16){
      float a = 0.f;
      #pragma unroll
      for (int d = 0; d < 64; d += 4){
        float4 qv = *(float4*)&q_s[i][d];
        float4 rk = *(const float4*)&rke[r * 64 + d];
        a += qv.x * rk.x + qv.y * rk.y + qv.z * rk.z + qv.w * rk.w;
      }
      qrk_s[i][r] = a;
    }
  }

  const int tmax = t0 + 15;
  const int cmax = tmax >> 7;
  const int sl = tid & 127;
  const int thalf = tid >> 7;

  // -------- phase 1: scores --------
  for (int c = 0; c <= cmax; c++){
    const int s0 = c << 7;
    __syncthreads();
    for (int x = tid; x < 128 * 16; x += 256){
      int r = x >> 4, d0 = (x & 15) << 2;
      *(float4*)&kv_s[r][d0] = *(const float4*)&kg[((size_t)(bh * 1024 + s0 + r)) * 64 + d0];
    }
    for (int x = tid; x < 64 * 32; x += 256){
      int r = x >> 5, c4 = (x & 31) << 2;
      *(float4*)&lr2_s[r][c4] = *(const float4*)&lr2g[((size_t)(bh * 64 + r)) * 1024 + s0 + c4];
    }
    __syncthreads();
    const int sg = s0 + sl;
    float4 kr[16];
    #pragma unroll
    for (int j = 0; j < 16; j++) kr[j] = *(float4*)&kv_s[sl][j << 2];
    #pragma unroll
    for (int ti = 0; ti < 8; ti++){
      const int r = (thalf << 3) + ti;
      const int gt = t0 + r;
      const int diff = gt - sg;
      if (diff < 0){ p_s[r][sg] = -1e30f; continue; }
      float acc = 0.f;
      #pragma unroll
      for (int j = 0; j < 16; j++){
        float4 qv = *(float4*)&q_s[r][j << 2];
        acc += qv.x * kr[j].x + qv.y * kr[j].y + qv.z * kr[j].z + qv.w * kr[j].w;
      }
      const int rid = (diff < 32) ? (32 - diff) : 0;
      float logit = (acc + qrk_s[r][rid]) * 0.125f;
      const size_t pidx = ((size_t)(b * 1024 + gt)) * 1024 + sg;
      const int rl = rel[pidx];
      const int mm = lrmap[pidx];
      const float td = tds[((size_t)(bh * 1024 + gt)) * 1024 + sg];
      logit = logit * relw_s[rl] + td + lr1_s[r][mm] + lr2_s[mm][sl];
      p_s[r][sg] = logit * 0.70710678118654752f;
    }
  }
  __syncthreads();

  // -------- phase 1.5: softmax (unnormalized exp + row sums) --------
  const int slim = (cmax + 1) << 7;
  #pragma unroll
  for (int rr = 0; rr < 4; rr++){
    const int r = (wave << 2) + rr;
    float mx = -3e38f;
    for (int s = lane; s < slim; s += 64) mx = fmaxf(mx, p_s[r][s]);
    #pragma unroll
    for (int off = 32; off; off >>= 1) mx = fmaxf(mx, __shfl_xor(mx, off));
    float sum = 0.f;
    for (int s = lane; s < slim; s += 64){
      float e = __expf(p_s[r][s] - mx);
      p_s[r][s] = e;
      sum += e;
    }
    #pragma unroll
    for (int off = 32; off; off >>= 1) sum += __shfl_xor(sum, off);
    if (lane == 0) S_s[r] = sum;
  }

  // -------- phase 2: PV --------
  const int trow = tid >> 4;
  const int dgrp = tid & 15;
  const int gt2 = t0 + trow;
  float o0 = 0, o1 = 0, o2 = 0, o3 = 0;
  for (int c = 0; c <= cmax; c++){
    const int s0 = c << 7;
    __syncthreads();
    for (int x = tid; x < 128 * 16; x += 256){
      int r = x >> 4, d0 = (x & 15) << 2;
      *(float4*)&kv_s[r][d0] = *(const float4*)&vg[((size_t)(bh * 1024 + s0 + r)) * 64 + d0];
    }
    __syncthreads();
    const float* prow = &p_s[trow][s0];
    #pragma unroll 8
    for (int s = 0; s < 128; s++){
      float pv = prow[s];
      float4 v4 = *(float4*)&kv_s[s][dgrp << 2];
      o0 += pv * v4.x; o1 += pv * v4.y; o2 += pv * v4.z; o3 += pv * v4.w;
    }
  }

  // -------- rel_v term + finalize --------
  float psum = 0.f, r0a = 0, r1a = 0, r2a = 0, r3a = 0;
  #pragma unroll
  for (int rr = 1; rr <= 32; rr++){
    int s = gt2 - 32 + rr;
    if (s >= 0){
      float pv = p_s[trow][s];
      psum += pv;
      float4 r4 = *(float4*)&rv_s[rr][dgrp << 2];
      r0a += pv * r4.x; r1a += pv * r4.y; r2a += pv * r4.z; r3a += pv * r4.w;
    }
  }
  const float S = S_s[trow];
  float pr0 = S - psum; pr0 = pr0 > 0.f ? pr0 : 0.f;
  float4 rz = *(float4*)&rv_s[0][dgrp << 2];
  r0a += pr0 * rz.x; r1a += pr0 * rz.y; r2a += pr0 * rz.z; r3a += pr0 * rz.w;
  const float inv = 1.0f / S;
  o0 = (o0 + r0a) * inv; o1 = (o1 + r1a) * inv; o2 = (o2 + r2a) * inv; o3 = (o3 + r3a) * inv;
  ushort4 ob;
  ob.x = f32_to_bf16_rne(o0); ob.y = f32_to_bf16_rne(o1);
  ob.z = f32_to_bf16_rne(o2); ob.w = f32_to_bf16_rne(o3);
  *(ushort4*)&yb[((size_t)(b * 1024 + gt2)) * 1024 + (h << 6) + (dgrp << 2)] = ob;
}

// ---------------- launch ----------------
extern "C" void kernel_launch(void* const* d_in, const int* in_sizes, int n_in,
                              void* d_out, int out_size, void* d_ws, size_t ws_size,
                              hipStream_t stream)
{
  const float* x    = (const float*)d_in[0];
  const int*   rel  = (const int*)d_in[1];
  const float* tds  = (const float*)d_in[2];
  const float* LRQ  = (const float*)d_in[3];
  const float* LRK  = (const float*)d_in[4];
  const int*   lrmap= (const int*)d_in[5];
  const float* caw  = (const float*)d_in[6];
  const float* cab  = (const float*)d_in[7];
  const float* cpw  = (const float*)d_in[8];
  const float* cpb  = (const float*)d_in[9];
  const float* relw = (const float*)d_in[10];
  const float* rke  = (const float*)d_in[11];
  const float* rve  = (const float*)d_in[12];
  float* out = (float*)d_out;

  char* ws = (char*)d_ws;
  unsigned short* xb  = (unsigned short*)(ws);                       //  8 MB
  unsigned short* waT = (unsigned short*)(ws + ((size_t)8  << 20));  //  6 MB
  unsigned short* wpT = (unsigned short*)(ws + ((size_t)14 << 20));  //  2 MB
  float* qkv          = (float*)(ws + ((size_t)16 << 20));           // 48 MB  [3][B][H][T][D]
  float* lr2          = (float*)(ws + ((size_t)64 << 20));           // 16 MB  [B*H][64][T]
  unsigned short* yb  = (unsigned short*)(ws + ((size_t)80 << 20));  //  8 MB

  const size_t BHTD = (size_t)4 * 16 * 1024 * 64;
  const float* qptr = qkv;
  const float* kptr = qkv + BHTD;
  const float* vptr = qkv + 2 * BHTD;

  cvt_bf16<<<4096, 256, 0, stream>>>(x, xb, 4096 * 1024 / 4);
  transpose_cvt<<<dim3(3072 / 32, 1024 / 32), 256, 0, stream>>>(caw, waT, 1024, 3072);
  transpose_cvt<<<dim3(1024 / 32, 1024 / 32), 256, 0, stream>>>(cpw, wpT, 1024, 1024);
  gemm_bf16<1><<<dim3(32, 24), 256, 0, stream>>>(xb, waT, cab, qkv, 4096, 3072, 1024);
  lr2_kernel<<<dim3(16, 4, 64), 64, 0, stream>>>(LRQ, kptr, lr2);
  attn_kernel<<<4096, 256, 0, stream>>>(qptr, kptr, vptr, rel, tds, relw, lrmap,
                                        LRK, lr2, rke, rve, yb);
  gemm_bf16<0><<<dim3(32, 8), 256, 0, stream>>>(yb, wpT, cpb, out, 4096, 1024, 1024);
}

// Round 2
// 1118.000 us; speedup vs baseline: 1.1967x; 1.1967x over previous
//
#include <hip/hip_runtime.h>

typedef __attribute__((ext_vector_type(8))) short short8;
typedef __attribute__((ext_vector_type(4))) float fx4;

__device__ __forceinline__ unsigned short f32_to_bf16_rne(float f){
  unsigned int u = __float_as_uint(f);
  u += 0x7fffu + ((u >> 16) & 1u);
  return (unsigned short)(u >> 16);
}

// ---------------- convert f32 -> bf16 (flat) ----------------
__global__ void cvt_bf16(const float* __restrict__ in, unsigned short* __restrict__ out, int n4){
  int i = blockIdx.x * blockDim.x + threadIdx.x;
  if (i < n4){
    float4 v = ((const float4*)in)[i];
    ushort4 o;
    o.x = f32_to_bf16_rne(v.x); o.y = f32_to_bf16_rne(v.y);
    o.z = f32_to_bf16_rne(v.z); o.w = f32_to_bf16_rne(v.w);
    ((ushort4*)out)[i] = o;
  }
}

// ---------------- transpose + convert: in[R][C] f32 -> out[C][R] bf16 ----------------
__global__ void transpose_cvt(const float* __restrict__ in, unsigned short* __restrict__ out,
                              int R, int C){
  __shared__ float tile[32][33];
  int c0 = blockIdx.x * 32, r0 = blockIdx.y * 32;
  int lc = threadIdx.x & 31, lr = threadIdx.x >> 5;
  #pragma unroll
  for (int i = 0; i < 32; i += 8)
    tile[lr + i][lc] = in[(size_t)(r0 + lr + i) * C + c0 + lc];
  __syncthreads();
  #pragma unroll
  for (int i = 0; i < 32; i += 8)
    out[(size_t)(c0 + lr + i) * R + r0 + lc] = f32_to_bf16_rne(tile[lc][lr + i]);
}

// ---------------- bf16 MFMA GEMM: C[M][N] = A[M][K] * BT[N][K]^T + bias ----------------
template<int MODE>
__global__ __launch_bounds__(256) void gemm_bf16(const unsigned short* __restrict__ A,
    const unsigned short* __restrict__ BT, const float* __restrict__ bias,
    float* __restrict__ out, int M, int N, int K)
{
  __shared__ unsigned short a_s[2][128 * 32];
  __shared__ unsigned short b_s[2][128 * 32];
  const int tid = threadIdx.x;
  const int brow = blockIdx.x * 128, bcol = blockIdx.y * 128;
  const int lane = tid & 63;
  const int wave = tid >> 6;
  const int wm = (wave >> 1) * 64, wn = (wave & 1) * 64;
  const int lanr = lane & 15, laneq = lane >> 4;

  fx4 acc[4][4];
  const fx4 zero = {0.f, 0.f, 0.f, 0.f};
  #pragma unroll
  for (int m = 0; m < 4; m++)
    #pragma unroll
    for (int n = 0; n < 4; n++) acc[m][n] = zero;

  short8 ra[2], rb[2];
  auto gload = [&](int k0){
    #pragma unroll
    for (int i = 0; i < 2; i++){
      int cc = tid + (i << 8);
      int row = cc >> 2, seg = (cc & 3) << 3;
      ra[i] = *(const short8*)(A  + (size_t)(brow + row) * K + k0 + seg);
      rb[i] = *(const short8*)(BT + (size_t)(bcol + row) * K + k0 + seg);
    }
  };
  auto lwrite = [&](int bufi){
    #pragma unroll
    for (int i = 0; i < 2; i++){
      int cc = tid + (i << 8);
      *(short8*)&a_s[bufi][cc * 8] = ra[i];
      *(short8*)&b_s[bufi][cc * 8] = rb[i];
    }
  };

  gload(0); lwrite(0); __syncthreads();
  const int NT = K / 32;
  int buf = 0;
  for (int t = 0; t < NT; t++){
    if (t + 1 < NT) gload((t + 1) * 32);
    short8 af[4], bfr[4];
    #pragma unroll
    for (int m = 0; m < 4; m++)
      af[m] = *(short8*)&a_s[buf][(wm + m * 16 + lanr) * 32 + laneq * 8];
    #pragma unroll
    for (int n = 0; n < 4; n++)
      bfr[n] = *(short8*)&b_s[buf][(wn + n * 16 + lanr) * 32 + laneq * 8];
    #pragma unroll
    for (int m = 0; m < 4; m++)
      #pragma unroll
      for (int n = 0; n < 4; n++)
        acc[m][n] = __builtin_amdgcn_mfma_f32_16x16x32_bf16(af[m], bfr[n], acc[m][n], 0, 0, 0);
    __syncthreads();
    if (t + 1 < NT){ lwrite(buf ^ 1); __syncthreads(); }
    buf ^= 1;
  }

  #pragma unroll
  for (int m = 0; m < 4; m++){
    #pragma unroll
    for (int n = 0; n < 4; n++){
      const int col = bcol + wn + n * 16 + lanr;
      const float bv = bias[col];
      #pragma unroll
      for (int r = 0; r < 4; r++){
        const int row = brow + wm + m * 16 + laneq * 4 + r;
        const float val = acc[m][n][r] + bv;
        if constexpr (MODE == 0){
          out[(size_t)row * N + col] = val;
        } else {
          const int which = col >> 10, cc2 = col & 1023;
          const int hh = cc2 >> 6, dd = cc2 & 63;
          const int bb = row >> 10, tt2 = row & 1023;
          out[((((size_t)which * 4 + bb) * 16 + hh) * 1024 + tt2) * 64 + dd] = val;
        }
      }
    }
  }
}

// ---------------- lr2[bh][s][n] = 0.125 * dot(LR_Q[h][n], k[bh][s]) ----------------
// layout [bh][s][n] so producer writes and attn staging are both coalesced.
__global__ __launch_bounds__(256) void lr2_kernel(const float* __restrict__ LRQ,
    const float* __restrict__ kg, float* __restrict__ lr2g)
{
  __shared__ float lqT[64][68];   // [d][n]
  __shared__ float k_s[64][68];   // [s][d]
  const int tid = threadIdx.x;
  const int bh = blockIdx.x >> 4;
  const int s0 = (blockIdx.x & 15) << 6;
  const int h = bh & 15;
  #pragma unroll
  for (int p = 0; p < 4; p++){
    int x = (p << 8) + tid;
    int r = x >> 4, d4 = (x & 15) << 2;
    float4 v = *(const float4*)&LRQ[((size_t)((h << 6) + r) << 6) + d4];
    lqT[d4 + 0][r] = v.x; lqT[d4 + 1][r] = v.y; lqT[d4 + 2][r] = v.z; lqT[d4 + 3][r] = v.w;
    *(float4*)&k_s[r][d4] = *(const float4*)&kg[((size_t)((bh << 10) + s0 + r) << 6) + d4];
  }
  __syncthreads();
  const int n = tid & 63, w = tid >> 6;
  float lqr[64];
  #pragma unroll
  for (int d = 0; d < 64; d++) lqr[d] = lqT[d][n];
  #pragma unroll
  for (int i = 0; i < 16; i++){
    const int s = (w << 4) + i;
    float a = 0.f;
    #pragma unroll
    for (int j = 0; j < 16; j++){
      float4 k4 = *(float4*)&k_s[s][j << 2];
      a += lqr[4*j]*k4.x + lqr[4*j+1]*k4.y + lqr[4*j+2]*k4.z + lqr[4*j+3]*k4.w;
    }
    lr2g[((size_t)((bh << 10) + s0 + s) << 6) + n] = a * 0.125f;
  }
}

// ---------------- fused relative attention (online softmax, chunk=64) ----------------
// grid: 4096 blocks; decode: h innermost (L2 reuse of rel/lrmap), t-tiles heavy-first.
__global__ __launch_bounds__(256, 3) void attn_kernel(
    const float* __restrict__ qg, const float* __restrict__ kg, const float* __restrict__ vg,
    const int* __restrict__ rel, const float* __restrict__ tds,
    const float* __restrict__ relw, const int* __restrict__ lrmap,
    const float* __restrict__ LRK, const float* __restrict__ lr2g,
    const float* __restrict__ rke, const float* __restrict__ rve,
    unsigned short* __restrict__ yb)
{
  __shared__ float k_s[64][64];     // XOR-16 swizzled float4 slots
  __shared__ float lr2_s[64][68];   // [s][n]
  __shared__ float p_s[16][64];
  __shared__ float q_s[16][64];
  __shared__ float lr1_s[16][64];
  __shared__ float qrk_s[16][36];
  __shared__ float relw_s[64];
  __shared__ float scale_s[16];
  __shared__ float S_s[16];

  const int tid = threadIdx.x;
  const int bid = blockIdx.x;
  const int h = bid & 15;
  const int rest = bid >> 4;
  const int b = rest & 3;
  const int tt = 63 - (rest >> 2);        // heavy tiles first
  const int t0 = tt << 4;
  const int bh = (b << 4) + h;
  const int lane = tid & 63;
  const int wave = tid >> 6;

  // ---- prologue: stage tables ----
  if (tid < 64) relw_s[tid] = relw[tid * 16 + h];
  { int i = tid >> 4, d4 = (tid & 15) << 2;
    *(float4*)&q_s[i][d4] = *(const float4*)&qg[((size_t)((bh << 10) + t0 + i) << 6) + d4]; }
  #pragma unroll
  for (int p = 0; p < 4; p++){          // LRK[h] into k_s, swizzled
    int x = (p << 8) + tid;
    int row = x >> 4, j = x & 15;
    *(float4*)&k_s[row][(j ^ (row & 15)) << 2] =
      *(const float4*)&LRK[((size_t)((h << 6) + row) << 6) + (j << 2)];
  }
  __syncthreads();

  // lr1[i][n] = 0.125 * dot(q[i], LR_K[h][n])
  { int i = tid >> 4, n0 = (tid & 15) << 2;
    float a0 = 0, a1 = 0, a2 = 0, a3 = 0;
    #pragma unroll
    for (int j = 0; j < 16; j++){
      float4 qv = *(float4*)&q_s[i][j << 2];
      float4 x0 = *(float4*)&k_s[n0 + 0][(j ^ ((n0 + 0) & 15)) << 2];
      float4 x1 = *(float4*)&k_s[n0 + 1][(j ^ ((n0 + 1) & 15)) << 2];
      float4 x2 = *(float4*)&k_s[n0 + 2][(j ^ ((n0 + 2) & 15)) << 2];
      float4 x3 = *(float4*)&k_s[n0 + 3][(j ^ ((n0 + 3) & 15)) << 2];
      a0 += qv.x*x0.x + qv.y*x0.y + qv.z*x0.z + qv.w*x0.w;
      a1 += qv.x*x1.x + qv.y*x1.y + qv.z*x1.z + qv.w*x1.w;
      a2 += qv.x*x2.x + qv.y*x2.y + qv.z*x2.z + qv.w*x2.w;
      a3 += qv.x*x3.x + qv.y*x3.y + qv.z*x3.z + qv.w*x3.w;
    }
    lr1_s[i][n0 + 0] = a0 * 0.125f;
    lr1_s[i][n0 + 1] = a1 * 0.125f;
    lr1_s[i][n0 + 2] = a2 * 0.125f;
    lr1_s[i][n0 + 3] = a3 * 0.125f;
  }
  // qrk[i][r] = dot(q[i], rel_k_emb[r])
  { int i = tid >> 4;
    for (int r = tid & 15; r < 33; r += 16){
      float a = 0.f;
      #pragma unroll
      for (int j = 0; j < 16; j++){
        float4 qv = *(float4*)&q_s[i][j << 2];
        float4 rk = *(const float4*)&rke[(r << 6) + (j << 2)];
        a += qv.x*rk.x + qv.y*rk.y + qv.z*rk.z + qv.w*rk.w;
      }
      qrk_s[i][r] = a;
    }
  }

  // per-wave online-softmax state: wave owns rows wave*4..wave*4+3
  float m_reg[4], S_reg[4];
  #pragma unroll
  for (int j = 0; j < 4; j++){ m_reg[j] = -1e30f; S_reg[j] = 0.f; }
  // PV-mapping accumulators
  const int trow = tid >> 4, dgrp = tid & 15;
  const int gt2 = t0 + trow;
  float o0 = 0, o1 = 0, o2 = 0, o3 = 0;
  float ra0 = 0, ra1 = 0, ra2 = 0, ra3 = 0, ptail = 0;
  const int sl = lane;
  const int cmax = (t0 + 15) >> 6;

  for (int c = 0; c <= cmax; c++){
    const int s0 = c << 6;
    __syncthreads();
    // stage k chunk (swizzled) + lr2 chunk
    #pragma unroll
    for (int p = 0; p < 4; p++){
      int x = (p << 8) + tid;
      int row = x >> 4, j = x & 15;
      *(float4*)&k_s[row][(j ^ (row & 15)) << 2] =
        *(const float4*)&kg[((size_t)((bh << 10) + s0 + row) << 6) + (j << 2)];
      *(float4*)&lr2_s[row][j << 2] =
        *(const float4*)&lr2g[((size_t)((bh << 10) + s0 + row) << 6) + (j << 2)];
    }
    __syncthreads();

    // ---- scores + online softmax ----
    float4 kr[16];
    #pragma unroll
    for (int j = 0; j < 16; j++) kr[j] = *(float4*)&k_s[sl][(j ^ (sl & 15)) << 2];
    const int sg = s0 + sl;
    #pragma unroll
    for (int jj = 0; jj < 4; jj++){
      const int r = (wave << 2) + jj;
      const int gt = t0 + r;
      const int diff = gt - sg;
      float sc = -1e30f;
      if (diff >= 0){
        float acc = 0.f;
        #pragma unroll
        for (int j = 0; j < 16; j++){
          float4 qv = *(float4*)&q_s[r][j << 2];
          acc += qv.x*kr[j].x + qv.y*kr[j].y + qv.z*kr[j].z + qv.w*kr[j].w;
        }
        const int rid = (diff < 32) ? (32 - diff) : 0;
        float logit = (acc + qrk_s[r][rid]) * 0.125f;
        const size_t pidx = (((size_t)(b << 10) + gt) << 10) + sg;
        const int rl = rel[pidx];
        const int mm = lrmap[pidx];
        const float td = tds[(((size_t)(bh << 10) + gt) << 10) + sg];
        logit = logit * relw_s[rl] + td + lr1_s[r][mm] + lr2_s[sl][mm];
        sc = logit * 0.70710678118654752f;
      }
      float mx = sc;
      #pragma unroll
      for (int off = 32; off; off >>= 1) mx = fmaxf(mx, __shfl_xor(mx, off));
      const float mn = fmaxf(m_reg[jj], mx);
      const float pv = (diff >= 0) ? __expf(sc - mn) : 0.f;
      float sum = pv;
      #pragma unroll
      for (int off = 32; off; off >>= 1) sum += __shfl_xor(sum, off);
      const float scl = __expf(m_reg[jj] - mn);
      S_reg[jj] = S_reg[jj] * scl + sum;
      m_reg[jj] = mn;
      p_s[r][sl] = pv;
      if (lane == 0) scale_s[r] = scl;
    }
    __syncthreads();

    // ---- PV + online rel_v tail ----
    const float os = scale_s[trow];
    o0 *= os; o1 *= os; o2 *= os; o3 *= os;
    ra0 *= os; ra1 *= os; ra2 *= os; ra3 *= os; ptail *= os;
    if (s0 <= gt2){
      const float* vbase = &vg[((size_t)((bh << 10) + s0)) << 6];
      const int smax = min(63, gt2 - s0);
      for (int s = 0; s <= smax; s++){
        const float pv = p_s[trow][s];
        float4 v4 = *(const float4*)&vbase[(s << 6) + (dgrp << 2)];
        o0 += pv*v4.x; o1 += pv*v4.y; o2 += pv*v4.z; o3 += pv*v4.w;
      }
      const int lo = max(s0, gt2 - 31);
      const int hi = min(s0 + 63, gt2);
      for (int s = lo; s <= hi; s++){
        const float pv = p_s[trow][s - s0];
        ptail += pv;
        float4 r4 = *(const float4*)&rve[((s - gt2 + 32) << 6) + (dgrp << 2)];
        ra0 += pv*r4.x; ra1 += pv*r4.y; ra2 += pv*r4.z; ra3 += pv*r4.w;
      }
    }
  }

  // publish row sums
  if (lane == 0){
    #pragma unroll
    for (int j = 0; j < 4; j++) S_s[(wave << 2) + j] = S_reg[j];
  }
  __syncthreads();

  const float S = S_s[trow];
  float pr0 = S - ptail; pr0 = fmaxf(pr0, 0.f);
  float4 rz = *(const float4*)&rve[dgrp << 2];
  const float inv = 1.0f / S;
  o0 = (o0 + ra0 + pr0 * rz.x) * inv;
  o1 = (o1 + ra1 + pr0 * rz.y) * inv;
  o2 = (o2 + ra2 + pr0 * rz.z) * inv;
  o3 = (o3 + ra3 + pr0 * rz.w) * inv;
  ushort4 ob;
  ob.x = f32_to_bf16_rne(o0); ob.y = f32_to_bf16_rne(o1);
  ob.z = f32_to_bf16_rne(o2); ob.w = f32_to_bf16_rne(o3);
  *(ushort4*)&yb[((size_t)((b << 10) + gt2) << 10) + (h << 6) + (dgrp << 2)] = ob;
}

// ---------------- launch ----------------
extern "C" void kernel_launch(void* const* d_in, const int* in_sizes, int n_in,
                              void* d_out, int out_size, void* d_ws, size_t ws_size,
                              hipStream_t stream)
{
  const float* x    = (const float*)d_in[0];
  const int*   rel  = (const int*)d_in[1];
  const float* tds  = (const float*)d_in[2];
  const float* LRQ  = (const float*)d_in[3];
  const float* LRK  = (const float*)d_in[4];
  const int*   lrmap= (const int*)d_in[5];
  const float* caw  = (const float*)d_in[6];
  const float* cab  = (const float*)d_in[7];
  const float* cpw  = (const float*)d_in[8];
  const float* cpb  = (const float*)d_in[9];
  const float* relw = (const float*)d_in[10];
  const float* rke  = (const float*)d_in[11];
  const float* rve  = (const float*)d_in[12];
  float* out = (float*)d_out;

  char* ws = (char*)d_ws;
  unsigned short* xb  = (unsigned short*)(ws);                       //  8 MB
  unsigned short* waT = (unsigned short*)(ws + ((size_t)8  << 20));  //  6 MB
  unsigned short* wpT = (unsigned short*)(ws + ((size_t)14 << 20));  //  2 MB
  float* qkv          = (float*)(ws + ((size_t)16 << 20));           // 48 MB  [3][B][H][T][D]
  float* lr2          = (float*)(ws + ((size_t)64 << 20));           // 16 MB  [B*H][T][64]
  unsigned short* yb  = (unsigned short*)(ws + ((size_t)80 << 20));  //  8 MB

  const size_t BHTD = (size_t)4 * 16 * 1024 * 64;
  const float* qptr = qkv;
  const float* kptr = qkv + BHTD;
  const float* vptr = qkv + 2 * BHTD;

  cvt_bf16<<<4096, 256, 0, stream>>>(x, xb, 4096 * 1024 / 4);
  transpose_cvt<<<dim3(3072 / 32, 1024 / 32), 256, 0, stream>>>(caw, waT, 1024, 3072);
  transpose_cvt<<<dim3(1024 / 32, 1024 / 32), 256, 0, stream>>>(cpw, wpT, 1024, 1024);
  gemm_bf16<1><<<dim3(32, 24), 256, 0, stream>>>(xb, waT, cab, qkv, 4096, 3072, 1024);
  lr2_kernel<<<dim3(1024), 256, 0, stream>>>(LRQ, kptr, lr2);
  attn_kernel<<<4096, 256, 0, stream>>>(qptr, kptr, vptr, rel, tds, relw, lrmap,
                                        LRK, lr2, rke, rve, yb);
  gemm_bf16<0><<<dim3(32, 8), 256, 0, stream>>>(yb, wpT, cpb, out, 4096, 1024, 1024);
}